// Round 2
// baseline (351.692 us; speedup 1.0000x reference)
//
#include <hip/hip_runtime.h>

#define HID 32
#define SEQ 512
#define GROUPS_PER_BLOCK 8
#define BLOCK (GROUPS_PER_BLOCK * 32)

typedef float v2f __attribute__((ext_vector_type(2)));

__device__ __forceinline__ float fast_exp(float x) {
    // e^x = 2^(x * log2(e)), v_exp_f32 ~1 ulp
    return __builtin_amdgcn_exp2f(x * 1.44269504088896340736f);
}
__device__ __forceinline__ float fast_rcp(float x) {
    return __builtin_amdgcn_rcpf(x);
}
__device__ __forceinline__ float sigmoid_f(float x) {
    return fast_rcp(1.0f + fast_exp(-x));
}
__device__ __forceinline__ float tanh_f(float x) {
    // tanh(x) = 1 - 2/(1 + e^{2x}); saturates correctly at +/-inf
    return 1.0f - 2.0f * fast_rcp(1.0f + fast_exp(2.0f * x));
}

// Broadcast lane J (0..31) within each 32-lane half of the wave.
// ds_swizzle BitMode: new_lane = ((lane & and) | or) ^ xor; offset = (xor<<10)|(or<<5)|and.
// Immediate offset -> no per-broadcast address VGPR setup (unlike __shfl's ds_bpermute).
#define BCAST32(v, J) \
    __int_as_float(__builtin_amdgcn_ds_swizzle(__float_as_int(v), ((J) << 5)))

// min-waves/EU = 1: occupancy is LAUNCH-limited (512 blocks -> 2 blocks/CU ->
// 2 waves/SIMD) so there is nothing to gain from a low arch-VGPR count.
// With (BLOCK, 2) the RA parked the 128 weight floats in AGPRs and issued
// 4 v_accvgpr_read per J-step (~128 extra VALU instrs/timestep, measured
// ~230 vs ~97 expected). (BLOCK, 1) raises the arch budget to 256 so the
// weights stay directly addressable by v_pk_fma_f32.
__global__ __launch_bounds__(BLOCK, 1) void lstm_fused_kernel(
    const float* __restrict__ x,       // [B, T, 1]
    const float* __restrict__ W_ih,    // [4H, 1]
    const float* __restrict__ W_hh,    // [4H, H] row-major
    const float* __restrict__ b_ih,    // [4H]
    const float* __restrict__ b_hh,    // [4H]
    const float* __restrict__ W_head,  // [1, H]
    const float* __restrict__ b_head,  // [1]
    float* __restrict__ out)           // [B, 1]
{
    // Stage W_hh transposed into LDS: Wl[j][g] with padded stride 129 (conflict-free)
    __shared__ float Wl[32 * 129];
    const int tid = threadIdx.x;
    for (int idx = tid; idx < 128 * 32; idx += BLOCK) {
        const int g = idx >> 5;   // gate-row 0..127
        const int j = idx & 31;   // hidden col 0..31
        Wl[j * 129 + g] = W_hh[idx];
    }
    __syncthreads();

    const int k   = tid & 31;   // hidden unit owned by this lane
    const int grp = tid >> 5;   // batch group within block (0..7)
    const int b   = blockIdx.x * GROUPS_PER_BLOCK + grp;

    // Weights as packed gate-pairs: w_if[j] = (Wi[k][j], Wf[k][j]), w_go[j] = (Wg, Wo).
    // Packed layout feeds v_pk_fma_f32: 2 FMAs/instr, same per-gate fma chain order
    // (bitwise-identical numerics vs. the scalar version).
    v2f w_if[HID], w_go[HID];
#pragma unroll
    for (int j = 0; j < HID; ++j) {
        w_if[j] = (v2f){ Wl[j * 129 +       k], Wl[j * 129 + 32 + k] };
        w_go[j] = (v2f){ Wl[j * 129 + 64 + k], Wl[j * 129 + 96 + k] };
    }
    // Pin the 128 weight floats into arch VGPRs: asm-opaque values cannot be
    // rematerialized from LDS by the scheduler.
#pragma unroll
    for (int j = 0; j < HID; ++j) {
        asm volatile("" : "+v"(w_if[j]), "+v"(w_go[j]));
    }

    const v2f bv_if = { b_ih[k]      + b_hh[k],      b_ih[32 + k] + b_hh[32 + k] };
    const v2f bv_go = { b_ih[64 + k] + b_hh[64 + k], b_ih[96 + k] + b_hh[96 + k] };
    const v2f uv_if = { W_ih[k],      W_ih[32 + k] };
    const v2f uv_go = { W_ih[64 + k], W_ih[96 + k] };

    const float* xb = x + (size_t)b * SEQ;  // I == 1, so x[b][t][0] = xb[t]

    float h = 0.0f, c = 0.0f;

#define JS(J) { \
        const float hj = BCAST32(h, J); \
        const v2f  hv = { hj, hj }; \
        aif = __builtin_elementwise_fma(w_if[J], hv, aif); \
        ago = __builtin_elementwise_fma(w_go[J], hv, ago); }

    for (int t0 = 0; t0 < SEQ; t0 += 32) {
        // lane k prefetches x[b][t0+k]; broadcast per-step via shuffle
        const float xv = xb[t0 + k];
#pragma unroll 4
        for (int tt = 0; tt < 32; ++tt) {
            const float xt = __shfl(xv, tt, 32);
            const v2f xtv = { xt, xt };
            v2f aif = __builtin_elementwise_fma(xtv, uv_if, bv_if);
            v2f ago = __builtin_elementwise_fma(xtv, uv_go, bv_go);
            JS(0)  JS(1)  JS(2)  JS(3)  JS(4)  JS(5)  JS(6)  JS(7)
            JS(8)  JS(9)  JS(10) JS(11) JS(12) JS(13) JS(14) JS(15)
            JS(16) JS(17) JS(18) JS(19) JS(20) JS(21) JS(22) JS(23)
            JS(24) JS(25) JS(26) JS(27) JS(28) JS(29) JS(30) JS(31)
            const float ig = sigmoid_f(aif.x);
            const float fg = sigmoid_f(aif.y);
            const float gg = tanh_f(ago.x);
            const float og = sigmoid_f(ago.y);
            c = __builtin_fmaf(fg, c, ig * gg);
            h = og * tanh_f(c);
        }
    }
#undef JS

    // head: out[b] = sum_k h[k] * W_head[0][k] + b_head[0]
    float v = h * W_head[k];
#pragma unroll
    for (int off = 16; off >= 1; off >>= 1)
        v += __shfl_xor(v, off, 32);
    if (k == 0) out[b] = v + b_head[0];
}

extern "C" void kernel_launch(void* const* d_in, const int* in_sizes, int n_in,
                              void* d_out, int out_size, void* d_ws, size_t ws_size,
                              hipStream_t stream) {
    const float* x      = (const float*)d_in[0];
    const float* W_ih   = (const float*)d_in[1];
    const float* W_hh   = (const float*)d_in[2];
    const float* b_ih   = (const float*)d_in[3];
    const float* b_hh   = (const float*)d_in[4];
    const float* W_head = (const float*)d_in[5];
    const float* b_head = (const float*)d_in[6];
    float* out = (float*)d_out;

    const int B = in_sizes[0] / SEQ;          // 4096
    const int grid = B / GROUPS_PER_BLOCK;    // 512 blocks

    lstm_fused_kernel<<<grid, BLOCK, 0, stream>>>(
        x, W_ih, W_hh, b_ih, b_hh, W_head, b_head, out);
}

// Round 3
// 343.701 us; speedup vs baseline: 1.0233x; 1.0233x over previous
//
#include <hip/hip_runtime.h>

#define HID 32
#define SEQ 512
#define GROUPS_PER_BLOCK 8
#define BLOCK (GROUPS_PER_BLOCK * 32)

typedef float v2f __attribute__((ext_vector_type(2)));

__device__ __forceinline__ float fast_exp(float x) {
    // e^x = 2^(x * log2(e)), v_exp_f32 ~1 ulp
    return __builtin_amdgcn_exp2f(x * 1.44269504088896340736f);
}
__device__ __forceinline__ float fast_rcp(float x) {
    return __builtin_amdgcn_rcpf(x);
}
__device__ __forceinline__ float sigmoid_f(float x) {
    return fast_rcp(1.0f + fast_exp(-x));
}
__device__ __forceinline__ float tanh_f(float x) {
    // tanh(x) = 1 - 2/(1 + e^{2x}); saturates correctly at +/-inf
    return 1.0f - 2.0f * fast_rcp(1.0f + fast_exp(2.0f * x));
}

// Broadcast lane J (0..31) within each 32-lane half of the wave.
// ds_swizzle BitMode: new_lane = ((lane & and) | or) ^ xor; offset = (xor<<10)|(or<<5)|and.
#define BCAST32(v, J) \
    __int_as_float(__builtin_amdgcn_ds_swizzle(__float_as_int(v), ((J) << 5)))

// Occupancy is LAUNCH-limited at 2 waves/SIMD (512 blocks -> 2 blocks/CU).
// waves_per_eu(1,2) tells the RA its occupancy target is <=2, lifting the
// register budget so there is no incentive to park values in AGPRs.
__global__ __launch_bounds__(BLOCK)
__attribute__((amdgpu_waves_per_eu(1, 2)))
void lstm_fused_kernel(
    const float* __restrict__ x,       // [B, T, 1]
    const float* __restrict__ W_ih,    // [4H, 1]
    const float* __restrict__ W_hh,    // [4H, H] row-major
    const float* __restrict__ b_ih,    // [4H]
    const float* __restrict__ b_hh,    // [4H]
    const float* __restrict__ W_head,  // [1, H]
    const float* __restrict__ b_head,  // [1]
    float* __restrict__ out)           // [B, 1]
{
    // Stage W_hh transposed into LDS: Wl[j][g] with padded stride 129 (conflict-free)
    __shared__ float Wl[32 * 129];
    const int tid = threadIdx.x;
    for (int idx = tid; idx < 128 * 32; idx += BLOCK) {
        const int g = idx >> 5;   // gate-row 0..127
        const int j = idx & 31;   // hidden col 0..31
        Wl[j * 129 + g] = W_hh[idx];
    }
    __syncthreads();

    const int k   = tid & 31;   // hidden unit owned by this lane
    const int grp = tid >> 5;   // batch group within block (0..7)
    const int b   = blockIdx.x * GROUPS_PER_BLOCK + grp;

    // Weights as packed gate-pairs: w_if[j] = (Wi[k][j], Wf[k][j]), w_go[j] = (Wg, Wo).
    // Packed layout feeds v_pk_fma_f32: 2 FMAs/instr, same per-gate fma chain order
    // (bitwise-identical numerics vs. the scalar version).
    v2f w_if[HID], w_go[HID];
#pragma unroll
    for (int j = 0; j < HID; ++j) {
        w_if[j] = (v2f){ Wl[j * 129 +       k], Wl[j * 129 + 32 + k] };
        w_go[j] = (v2f){ Wl[j * 129 + 64 + k], Wl[j * 129 + 96 + k] };
    }

    const v2f bv_if = { b_ih[k]      + b_hh[k],      b_ih[32 + k] + b_hh[32 + k] };
    const v2f bv_go = { b_ih[64 + k] + b_hh[64 + k], b_ih[96 + k] + b_hh[96 + k] };
    const v2f uv_if = { W_ih[k],      W_ih[32 + k] };
    const v2f uv_go = { W_ih[64 + k], W_ih[96 + k] };

    const float* xb = x + (size_t)b * SEQ;  // I == 1, so x[b][t][0] = xb[t]

    float h = 0.0f, c = 0.0f;

    // In-loop residency pin: empty volatile asm with "+v" ties forces ALL 128
    // weight floats to sit in arch VGPRs simultaneously at this point, EVERY
    // t0 iteration. Round-1's staging-time pins let the RA park the weights
    // in AGPRs and issue 4 v_accvgpr_read per JS (~130 extra VALU/step,
    // measured 234 vs ~95 expected). With a per-iteration pin, parking would
    // cost 128 copies/iter -> RA keeps them VGPR-resident. Emits 0 instrs.
#define PIN4(J) asm volatile("" : "+v"(w_if[J]), "+v"(w_go[J]), \
                                  "+v"(w_if[(J)+1]), "+v"(w_go[(J)+1]), \
                                  "+v"(w_if[(J)+2]), "+v"(w_go[(J)+2]), \
                                  "+v"(w_if[(J)+3]), "+v"(w_go[(J)+3]))
#define PIN_ALL() do { PIN4(0); PIN4(4); PIN4(8); PIN4(12); \
                       PIN4(16); PIN4(20); PIN4(24); PIN4(28); } while (0)

#define JS(J) { \
        const float hj = BCAST32(h, J); \
        const v2f  hv = { hj, hj }; \
        aif = __builtin_elementwise_fma(w_if[J], hv, aif); \
        ago = __builtin_elementwise_fma(w_go[J], hv, ago); }

    for (int t0 = 0; t0 < SEQ; t0 += 32) {
        PIN_ALL();
        // lane k prefetches x[b][t0+k]; broadcast per-step via shuffle
        const float xv = xb[t0 + k];
#pragma unroll 4
        for (int tt = 0; tt < 32; ++tt) {
            const float xt = __shfl(xv, tt, 32);
            const v2f xtv = { xt, xt };
            v2f aif = __builtin_elementwise_fma(xtv, uv_if, bv_if);
            v2f ago = __builtin_elementwise_fma(xtv, uv_go, bv_go);
            JS(0)  JS(1)  JS(2)  JS(3)  JS(4)  JS(5)  JS(6)  JS(7)
            JS(8)  JS(9)  JS(10) JS(11) JS(12) JS(13) JS(14) JS(15)
            JS(16) JS(17) JS(18) JS(19) JS(20) JS(21) JS(22) JS(23)
            JS(24) JS(25) JS(26) JS(27) JS(28) JS(29) JS(30) JS(31)
            const float ig = sigmoid_f(aif.x);
            const float fg = sigmoid_f(aif.y);
            const float gg = tanh_f(ago.x);
            const float og = sigmoid_f(ago.y);
            c = __builtin_fmaf(fg, c, ig * gg);
            h = og * tanh_f(c);
        }
    }
#undef JS
#undef PIN4
#undef PIN_ALL

    // head: out[b] = sum_k h[k] * W_head[0][k] + b_head[0]
    float v = h * W_head[k];
#pragma unroll
    for (int off = 16; off >= 1; off >>= 1)
        v += __shfl_xor(v, off, 32);
    if (k == 0) out[b] = v + b_head[0];
}

extern "C" void kernel_launch(void* const* d_in, const int* in_sizes, int n_in,
                              void* d_out, int out_size, void* d_ws, size_t ws_size,
                              hipStream_t stream) {
    const float* x      = (const float*)d_in[0];
    const float* W_ih   = (const float*)d_in[1];
    const float* W_hh   = (const float*)d_in[2];
    const float* b_ih   = (const float*)d_in[3];
    const float* b_hh   = (const float*)d_in[4];
    const float* W_head = (const float*)d_in[5];
    const float* b_head = (const float*)d_in[6];
    float* out = (float*)d_out;

    const int B = in_sizes[0] / SEQ;          // 4096
    const int grid = B / GROUPS_PER_BLOCK;    // 512 blocks

    lstm_fused_kernel<<<grid, BLOCK, 0, stream>>>(
        x, W_ih, W_hh, b_ih, b_hh, W_head, b_head, out);
}